// Round 6
// baseline (444.476 us; speedup 1.0000x reference)
//
#include <hip/hip_runtime.h>

#define N_V  20000
#define B_   8
#define F_   64
#define K_   6
#define OUT_ 64
#define NNZ_ 320000
#define BF   512    // B_*F_
#define NBUK N_V                    // one bucket per row
#define EPAD (NNZ_ + N_V * 7)       // buckets padded to multiple of 8 edges

typedef unsigned short ushort_t;
typedef unsigned int   uint_t;

using frag_ab = __attribute__((ext_vector_type(8))) short;  // 8 bf16 (4 VGPRs)
using frag_cd = __attribute__((ext_vector_type(4))) float;  // 4 f32 acc

// ---- bf16 helpers ----
__device__ __forceinline__ ushort_t f2bf(float f) {          // round-to-nearest-even
    uint_t u = __float_as_uint(f);
    u += 0x7FFFu + ((u >> 16) & 1u);
    return (ushort_t)(u >> 16);
}
__device__ __forceinline__ uint_t pack2(float lo, float hi) {
    return (uint_t)f2bf(lo) | ((uint_t)f2bf(hi) << 16);
}
__device__ __forceinline__ void unpack2(uint_t u, float& lo, float& hi) {
    lo = __uint_as_float(u << 16);
    hi = __uint_as_float(u & 0xFFFF0000u);
}

// -------- bucketed build: one bucket per row, padded to multiple of 8 --------

__global__ void hist_kernel(const int* __restrict__ rows, int* __restrict__ counts) {
    int e = blockIdx.x * 256 + threadIdx.x;
    if (e < NNZ_) atomicAdd(&counts[rows[e]], 1);
}

// single-block scan over all 20000 buckets: bp[i] = padded exclusive prefix,
// cursor[i] = bucket start for scatter. Replaces the old scan1/scan2/scan3 trio.
__global__ __launch_bounds__(1024) void scan_all(const int* __restrict__ counts,
                                                 int* __restrict__ bp,
                                                 int* __restrict__ cursor) {
    __shared__ int buf[1024];
    const int tid = threadIdx.x;
    int loc[20];
    int s = 0;
    if (tid < 1000) {
        const int base = tid * 20;
#pragma unroll
        for (int k = 0; k < 20; ++k) {
            loc[k] = s;
            s += (counts[base + k] + 7) & ~7;   // padded count
        }
    }
    buf[tid] = s;
    __syncthreads();
    for (int off = 1; off < 1024; off <<= 1) {
        int t = buf[tid];
        int add = (tid >= off) ? buf[tid - off] : 0;
        __syncthreads();
        buf[tid] = t + add;
        __syncthreads();
    }
    const int excl = buf[tid] - s;              // exclusive block offset
    if (tid < 1000) {
        const int base = tid * 20;
#pragma unroll
        for (int k = 0; k < 20; ++k) {
            const int p = excl + loc[k];
            bp[base + k] = p;
            cursor[base + k] = p;
        }
    }
    if (tid == 1023) bp[NBUK] = buf[1023];
}

// edges packed: {col, val_bits}; pad slots stay {0, 0.0f} from memset (zero contribution)
__global__ void scatter_kernel(const int* __restrict__ rows, const int* __restrict__ cols,
                               const float* __restrict__ vals, int* __restrict__ cursor,
                               int2* __restrict__ edges) {
    int e = blockIdx.x * 256 + threadIdx.x;
    if (e < NNZ_) {
        int pos = atomicAdd(&cursor[rows[e]], 1);
        edges[pos] = make_int2(cols[e], __float_as_int(vals[e]));
    }
}

// ---------------- fat prep: x->X0 bf16 (T layout [n][b][f]) + Wfrag pack ----------------
__global__ void prep_kernel(const float* __restrict__ x, uint_t* __restrict__ X0,
                            const float* __restrict__ W, ushort_t* __restrict__ Wfrag) {
    int blk = blockIdx.x;
    if (blk < 20000) {
        int idx = blk * 256 + threadIdx.x;      // over N_V*B_*32
        int f2 = idx & 31;
        int b  = (idx >> 5) & 7;
        int n  = idx >> 8;
        float2 v = *(const float2*)&x[((size_t)b * N_V + n) * F_ + f2 * 2];
        X0[n * 256 + b * 32 + f2] = pack2(v.x, v.y);
    } else {
        int idx = (blk - 20000) * 256 + threadIdx.x;
        if (idx < 12 * 4 * 64 * 8) {
            int j    = idx & 7;
            int lane = (idx >> 3) & 63;
            int ct   = (idx >> 9) & 3;
            int s    = idx >> 11;
            int o     = ct * 16 + (lane & 15);
            int kglob = s * 32 + ((lane >> 4) & 3) * 8 + j;
            Wfrag[idx] = f2bf(W[o * (K_ * F_) + kglob]);
        }
    }
}

// ---- consume one 8-edge block: unpack gathered line, FMA into row A or row B ----
#define CONS(Gv, vv, isA, accA, accB)                                          \
    {                                                                          \
        float e_[8];                                                           \
        unpack2(Gv.x, e_[0], e_[1]); unpack2(Gv.y, e_[2], e_[3]);              \
        unpack2(Gv.z, e_[4], e_[5]); unpack2(Gv.w, e_[6], e_[7]);              \
        if (isA) {                                                             \
            _Pragma("unroll")                                                  \
            for (int i_ = 0; i_ < 8; ++i_) accA[i_] = fmaf(vv, e_[i_], accA[i_]); \
        } else {                                                               \
            _Pragma("unroll")                                                  \
            for (int i_ = 0; i_ < 8; ++i_) accB[i_] = fmaf(vv, e_[i_], accB[i_]); \
        }                                                                      \
    }

// -------- SpMM: 4 rows (2 pair-streams) per wave, interleaved pipelines, XCD-chunked --------
// chunk = blockIdx & 7 -> XCD affinity (2.56 MB/XCD fits 4 MB L2).
// Lane l: edge sub = l>>3 within a block, features (l&7)*8 of the chunk (uint4 = 16B gather,
// 8 edges x 128 B per instruction). Two independent streams per wave double the in-flight
// gathers and overlap the start-up latencies; loop control is wave-uniform in SGPRs.
template <bool RECUR>
__global__ __launch_bounds__(256) void cheb_quad(const int* __restrict__ bp,
                                                 const int2* __restrict__ edges,
                                                 const ushort_t* __restrict__ Tprev,
                                                 const ushort_t* __restrict__ Tpp,
                                                 ushort_t* __restrict__ Tout) {
    const int wave = threadIdx.x >> 6, lane = threadIdx.x & 63;
    const int c    = blockIdx.x & 7;                     // chunk == batch index == XCD slot
    const int grp  = (blockIdx.x >> 3) * 4 + wave;       // [0, 5000): 4 rows per wave
    const int r0   = grp * 4;
    const int sub  = lane >> 3;                          // edge slot 0..7 within a block
    const int f8   = (lane & 7) << 3;                    // 8 features per lane

    // one vmem load covers all 5 bp values for rows r0..r0+4
    int bpv = bp[r0 + min(lane, 4)];
    const int st0  = __builtin_amdgcn_readfirstlane(__shfl(bpv, 0, 64));
    const int mid0 = __builtin_amdgcn_readfirstlane(__shfl(bpv, 1, 64));
    const int en0  = __builtin_amdgcn_readfirstlane(__shfl(bpv, 2, 64));
    const int mid1 = __builtin_amdgcn_readfirstlane(__shfl(bpv, 3, 64));
    const int en1  = __builtin_amdgcn_readfirstlane(__shfl(bpv, 4, 64));
    const int st1  = en0;

    const int n0 = (en0 - st0) >> 3;                     // 8-slot blocks per stream
    const int n1 = (en1 - st1) >> 3;
    const int maxit = max(n0, n1);

    const ushort_t* Tb = Tprev + (c << 6) + f8;          // + col*512 per edge
    const int2*     eb = edges + sub;

    float accA0[8], accB0[8], accA1[8], accB1[8];
#pragma unroll
    for (int i = 0; i < 8; ++i) { accA0[i] = 0.f; accB0[i] = 0.f; accA1[i] = 0.f; accB1[i] = 0.f; }

    if (maxit > 0) {
        // safe clamped block addressing (n==0 stream reads edges[0], value forced 0)
        const int safe0 = (n0 > 0) ? st0 : 0;
        const int safe1 = (n1 > 0) ? st1 : 0;
        const int last0 = safe0 + 8 * (max(n0, 1) - 1);
        const int last1 = safe1 + 8 * (max(n1, 1) - 1);

        int a0 = safe0, a1 = safe1;                      // block addr for iteration `it`
        // prologue: edges for it=0 and it=1 (4 independent loads), gathers for it=0
        int2 E0a = eb[a0];
        int2 E1a = eb[a1];
        int2 E0n = eb[min(safe0 + 8, last0)];
        int2 E1n = eb[min(safe1 + 8, last1)];
        uint4 G0 = *(const uint4*)(Tb + ((size_t)(uint_t)E0a.x << 9));
        uint4 G1 = *(const uint4*)(Tb + ((size_t)(uint_t)E1a.x << 9));
        float v0 = (n0 > 0) ? __int_as_float(E0a.y) : 0.f;
        float v1 = (n1 > 0) ? __int_as_float(E1a.y) : 0.f;

        for (int it = 0; it < maxit; ++it) {
            // issue gathers for it+1 (edge data prefetched last iteration)
            uint4 Gn0 = *(const uint4*)(Tb + ((size_t)(uint_t)E0n.x << 9));
            uint4 Gn1 = *(const uint4*)(Tb + ((size_t)(uint_t)E1n.x << 9));
            const float vn0 = (it + 1 < n0) ? __int_as_float(E0n.y) : 0.f;
            const float vn1 = (it + 1 < n1) ? __int_as_float(E1n.y) : 0.f;
            // prefetch edges for it+2 (clamped)
            int2 E0t = eb[min(a0 + 16, last0)];
            int2 E1t = eb[min(a1 + 16, last1)];
            // consume it (waits only on G0/G1; 6 younger vmem ops stay in flight)
            CONS(G0, v0, (a0 < mid0), accA0, accB0);
            CONS(G1, v1, (a1 < mid1), accA1, accB1);
            // shift pipelines
            G0 = Gn0; v0 = vn0; G1 = Gn1; v1 = vn1;
            E0n = E0t; E1n = E1t;
            a0 = min(a0 + 8, last0);
            a1 = min(a1 + 8, last1);
        }
    }

    // reduce across the 8 edge-subgroups (xor 8, 16, 32)
#pragma unroll
    for (int i = 0; i < 8; ++i) {
        accA0[i] += __shfl_xor(accA0[i], 8, 64); accA0[i] += __shfl_xor(accA0[i], 16, 64); accA0[i] += __shfl_xor(accA0[i], 32, 64);
        accB0[i] += __shfl_xor(accB0[i], 8, 64); accB0[i] += __shfl_xor(accB0[i], 16, 64); accB0[i] += __shfl_xor(accB0[i], 32, 64);
        accA1[i] += __shfl_xor(accA1[i], 8, 64); accA1[i] += __shfl_xor(accA1[i], 16, 64); accA1[i] += __shfl_xor(accA1[i], 32, 64);
        accB1[i] += __shfl_xor(accB1[i], 8, 64); accB1[i] += __shfl_xor(accB1[i], 16, 64); accB1[i] += __shfl_xor(accB1[i], 32, 64);
    }

    if (lane < 16) {
        const int isB = lane >> 3;                       // lanes 0-7: row A; 8-15: row B
        float s0[8], s1[8];
#pragma unroll
        for (int i = 0; i < 8; ++i) {
            s0[i] = isB ? accB0[i] : accA0[i];           // stream0 -> rows r0, r0+1
            s1[i] = isB ? accB1[i] : accA1[i];           // stream1 -> rows r0+2, r0+3
        }
        const size_t o0 = (size_t)(r0 + isB)     * BF + (c << 6) + f8;
        const size_t o1 = (size_t)(r0 + 2 + isB) * BF + (c << 6) + f8;
        if (RECUR) {
            uint4 up0 = *(const uint4*)(Tpp + o0);
            uint4 up1 = *(const uint4*)(Tpp + o1);
            float p[8];
            unpack2(up0.x, p[0], p[1]); unpack2(up0.y, p[2], p[3]);
            unpack2(up0.z, p[4], p[5]); unpack2(up0.w, p[6], p[7]);
#pragma unroll
            for (int i = 0; i < 8; ++i) s0[i] = fmaf(2.f, s0[i], -p[i]);
            unpack2(up1.x, p[0], p[1]); unpack2(up1.y, p[2], p[3]);
            unpack2(up1.z, p[4], p[5]); unpack2(up1.w, p[6], p[7]);
#pragma unroll
            for (int i = 0; i < 8; ++i) s1[i] = fmaf(2.f, s1[i], -p[i]);
        }
        uint4 w0, w1;
        w0.x = pack2(s0[0], s0[1]); w0.y = pack2(s0[2], s0[3]);
        w0.z = pack2(s0[4], s0[5]); w0.w = pack2(s0[6], s0[7]);
        w1.x = pack2(s1[0], s1[1]); w1.y = pack2(s1[2], s1[3]);
        w1.z = pack2(s1[4], s1[5]); w1.w = pack2(s1[6], s1[7]);
        *(uint4*)(Tout + o0) = w0;
        *(uint4*)(Tout + o1) = w1;
    }
}

// ---------------- FC via MFMA 16x16x32 bf16, 2 tiles/wave ----------------
__global__ __launch_bounds__(256) void fc_mfma(const ushort_t* __restrict__ X0,
                                               const ushort_t* __restrict__ T1,
                                               const ushort_t* __restrict__ T2,
                                               const ushort_t* __restrict__ T3,
                                               const ushort_t* __restrict__ T4,
                                               const ushort_t* __restrict__ T5,
                                               const ushort_t* __restrict__ Wfrag,
                                               const float* __restrict__ bias,
                                               float* __restrict__ out) {
    const int wave = threadIdx.x >> 6, lane = threadIdx.x & 63;
    const int quad = lane >> 4, col = lane & 15;
    const int tb = blockIdx.x * 128 + wave * 32;      // 2 tiles: tb, tb+16
    const int r0 = tb + col, r1 = tb + 16 + col;
    const ushort_t* Tbuf[6] = {X0, T1, T2, T3, T4, T5};

    frag_cd acc0[4], acc1[4];
#pragma unroll
    for (int ct = 0; ct < 4; ++ct) {
        acc0[ct] = (frag_cd){0.f, 0.f, 0.f, 0.f};
        acc1[ct] = (frag_cd){0.f, 0.f, 0.f, 0.f};
    }

#pragma unroll
    for (int s = 0; s < 12; ++s) {
        const int f0 = (s & 1) * 32 + quad * 8;
        frag_ab fa0 = *(const frag_ab*)(Tbuf[s >> 1] + (size_t)r0 * F_ + f0);
        frag_ab fa1 = *(const frag_ab*)(Tbuf[s >> 1] + (size_t)r1 * F_ + f0);
#pragma unroll
        for (int ct = 0; ct < 4; ++ct) {
            frag_ab bfr = *(const frag_ab*)(Wfrag + (((s * 4 + ct) * 64 + lane) << 3));
            acc0[ct] = __builtin_amdgcn_mfma_f32_16x16x32_bf16(fa0, bfr, acc0[ct], 0, 0, 0);
            acc1[ct] = __builtin_amdgcn_mfma_f32_16x16x32_bf16(fa1, bfr, acc1[ct], 0, 0, 0);
        }
    }

    // C/D: col = lane&15, row = quad*4 + reg
#pragma unroll
    for (int ct = 0; ct < 4; ++ct) {
        const int o = ct * 16 + col;
        const float bv = bias[o];
#pragma unroll
        for (int reg = 0; reg < 4; ++reg) {
            int ra = tb + quad * 4 + reg;
            int rb = ra + 16;
            out[(size_t)(ra & 7) * N_V * OUT_ + (size_t)(ra >> 3) * OUT_ + o] = acc0[ct][reg] + bv;
            out[(size_t)(rb & 7) * N_V * OUT_ + (size_t)(rb >> 3) * OUT_ + o] = acc1[ct][reg] + bv;
        }
    }
}

// ---------------- launcher ----------------

extern "C" void kernel_launch(void* const* d_in, const int* in_sizes, int n_in,
                              void* d_out, int out_size, void* d_ws, size_t ws_size,
                              hipStream_t stream) {
    const float* x    = (const float*)d_in[0];
    const int*   rows = (const int*)  d_in[1];
    const int*   cols = (const int*)  d_in[2];
    const float* vals = (const float*)d_in[3];
    const float* W    = (const float*)d_in[4];
    const float* bias = (const float*)d_in[5];
    float* out = (float*)d_out;

    const size_t TSZ = (size_t)N_V * BF;           // bf16 elements per T buffer
    ushort_t* T1 = (ushort_t*)d_ws;
    ushort_t* T2 = T1 + TSZ;
    ushort_t* T3 = T2 + TSZ;
    ushort_t* T4 = T3 + TSZ;
    ushort_t* T5 = T4 + TSZ;
    ushort_t* X0 = T5 + TSZ;
    ushort_t* Wfrag = X0 + TSZ;                    // 24576 ushorts
    int*  counts = (int*)(Wfrag + 24576);          // NBUK ints   } one contiguous
    int2* edges  = (int2*)(counts + NBUK);         // EPAD int2   } memset region
    int*  bp     = (int*)(edges + EPAD);           // NBUK+1 (+pad)
    int*  cursor = bp + NBUK + 64;                 // NBUK

    // single memset zeroes counts AND pad edge slots {col=0, val=0}
    hipMemsetAsync(counts, 0, NBUK * sizeof(int) + (size_t)EPAD * sizeof(int2), stream);
    hist_kernel<<<(NNZ_ + 255) / 256, 256, 0, stream>>>(rows, counts);
    scan_all<<<1, 1024, 0, stream>>>(counts, bp, cursor);
    scatter_kernel<<<(NNZ_ + 255) / 256, 256, 0, stream>>>(rows, cols, vals, cursor, edges);
    prep_kernel<<<20096, 256, 0, stream>>>(x, (uint_t*)X0, W, Wfrag);

    const int chebGrid = 1250 * 8;                 // (4-wave group of 4-row streams) x 8 chunks
    cheb_quad<false><<<chebGrid, 256, 0, stream>>>(bp, edges, X0, nullptr, T1);
    cheb_quad<true ><<<chebGrid, 256, 0, stream>>>(bp, edges, T1, X0, T2);
    cheb_quad<true ><<<chebGrid, 256, 0, stream>>>(bp, edges, T2, T1, T3);
    cheb_quad<true ><<<chebGrid, 256, 0, stream>>>(bp, edges, T3, T2, T4);
    cheb_quad<true ><<<chebGrid, 256, 0, stream>>>(bp, edges, T4, T3, T5);

    fc_mfma<<<(N_V * B_) / 128, 256, 0, stream>>>(X0, T1, T2, T3, T4, T5, Wfrag, bias, out);
}